// Round 5
// baseline (36714.560 us; speedup 1.0000x reference)
//
#include <hip/hip_runtime.h>

typedef unsigned int u32;
typedef unsigned short u16;
typedef unsigned long long u64;
#define DEV __device__ __forceinline__

// ---------------- sizes ----------------
#define T_DEC 300
#define NB    16
#define T_ENC 200
#define EDIM  512
#define ARNN  1024
#define PDIM  256
#define ADIM  128
#define NMEL  80
#define KATT  1792            // 256 prenet + 512 ctx + 1024 h_att
#define KDEC  2560            // 1024 h_att + 512 ctx + 1024 h_dec
#define NBLK  512             // 2 LSTM units per block
#define NTHR  128
#define SPIN  2000000         // poll-iteration limit

// ---------------- ws byte offsets ----------------
// counters page [0,4608): S1 leaves [32] @0 (stride 64B), abort @2048,
// S2cnt @2112, S2rep[32] @2560 (stride 64B, ends 4608)
#define WS_S1L    0
#define WS_ABORT  2048
#define WS_S2CNT  2112
#define WS_S2REP  2560
#define WS_ALIGN  4608                      // f32 [2][16][200] = 25600 (att-block-local)
#define WS_XA     30208                     // f32 [2][896][16][2] = 229376 (paired layout)
#define WS_XD     259584                    // f32 [2][1280][16][2] = 327680 (paired layout)
#define WS_PM     587264                    // u16 [3200][128] = 819200
#define WS_END    1406464
#define WS_ZERO   587264

// paired layout: element (k,b) lives at [(k>>1)*32 + 2*b + (k&1)]
#define XI(k,b) (((k) >> 1) * 32 + 2 * (b) + ((k) & 1))

// ---------------- out layout (f32 elements) ----------------
#define OUT_GATE  (NB*NMEL*T_DEC)           // 384000
#define OUT_ALIGN (OUT_GATE + NB*T_DEC)     // 388800

// ---------------- helpers ----------------
DEV float bflo(u32 u){ return __uint_as_float(u << 16); }
DEV float bfhi(u32 u){ return __uint_as_float(u & 0xffff0000u); }
DEV u16 f2bf(float f){
  u32 u = __float_as_uint(f);
  return (u16)((u + 0x7fffu + ((u >> 16) & 1u)) >> 16);
}
DEV float fsig(float x){ return 1.0f / (1.0f + __expf(-x)); }
DEV float ftanh(float x){
  float xx = fminf(15.0f, fmaxf(-15.0f, x));
  float e = __expf(2.0f * xx);
  return (e - 1.0f) / (e + 1.0f);
}

// ---- coherence-point accessors (sc1): no L2 dirty lines, no fences needed ----
DEV void ast (float* p, float v){ __hip_atomic_store(p, v, __ATOMIC_RELAXED, __HIP_MEMORY_SCOPE_AGENT); }
DEV void ast32(u32* p, u32 v)  { __hip_atomic_store(p, v, __ATOMIC_RELAXED, __HIP_MEMORY_SCOPE_AGENT); }
DEV int  ald (const int* p)    { return __hip_atomic_load(p, __ATOMIC_RELAXED, __HIP_MEMORY_SCOPE_AGENT); }
DEV void ald2f(const float* p, float& f0, float& f1){
  u64 v = __hip_atomic_load((const u64*)p, __ATOMIC_RELAXED, __HIP_MEMORY_SCOPE_AGENT);
  f0 = __uint_as_float((u32)v);
  f1 = __uint_as_float((u32)(v >> 32));
}
DEV void ast2f(float* p, float f0, float f1){
  u64 v = (u64)__float_as_uint(f0) | ((u64)__float_as_uint(f1) << 32);
  __hip_atomic_store((u64*)p, v, __ATOMIC_RELAXED, __HIP_MEMORY_SCOPE_AGENT);
}

// ---------------- Threefry-2x32-20 (JAX partitionable; R3/R7-verified) ----------------
__host__ __device__ inline void tf2x32(u32 k0, u32 k1, u32 x0, u32 x1, u32& o0, u32& o1){
  u32 k2 = k0 ^ k1 ^ 0x1BD11BDAu;
  x0 += k0; x1 += k1;
#define TFR(r) { x0 += x1; x1 = (x1 << r) | (x1 >> (32 - r)); x1 ^= x0; }
  TFR(13) TFR(15) TFR(26) TFR(6)  x0 += k1; x1 += k2 + 1u;
  TFR(17) TFR(29) TFR(16) TFR(24) x0 += k2; x1 += k0 + 2u;
  TFR(13) TFR(15) TFR(26) TFR(6)  x0 += k0; x1 += k1 + 3u;
  TFR(17) TFR(29) TFR(16) TFR(24) x0 += k1; x1 += k2 + 4u;
  TFR(13) TFR(15) TFR(26) TFR(6)  x0 += k2; x1 += k0 + 5u;
#undef TFR
  o0 = x0; o1 = x1;
}
DEV bool keep_mask(u32 k0, u32 k1, u32 idx){
  u32 a, b; tf2x32(k0, k1, 0u, idx, a, b);
  return (((a ^ b) >> 31) & 1u) == 0u;
}

// ---------------- params ----------------
struct KParams {
  const float *memory, *mels, *pw1, *pw2, *mem_w, *qw, *vw;
  const float *aih, *ahh, *abi, *abh, *dih, *dhh, *dbi, *dbh;
  const float *prw, *prb, *gw, *gb;
  char* ws; float* out;
  u32 k10, k11, k20, k21;
};

__global__ void sentinel_kernel(float* out){ if (threadIdx.x == 0) out[0] = 123.0f; }

// ---------------- sync primitives (fence-free) ----------------
// Post S1: drain own sc1 traffic, join block, add to this block's leaf (32 leaves,
// 16 blocks each -> max 16 serialized RMWs per line, leaves parallel across slices).
DEV void postS1(int* S1L, int blk, int tid){
  asm volatile("s_waitcnt vmcnt(0)" ::: "memory");
  __syncthreads();
  if (tid == 0)
    (void)__hip_atomic_fetch_add(&S1L[(blk >> 4) * 16], 1, __ATOMIC_RELAXED, __HIP_MEMORY_SCOPE_AGENT);
}

// Wait all 32 S1 leaves >= target (service blocks only). Wave 0 polls 32 lines.
DEV bool waitS1(int* S1L, int* abortf, int target, int tid, float* out){
  int aborted = 0;
  if (tid < 64){
    int tries = 0;
    for (;;){
      int v = (tid < 32) ? ald(&S1L[tid * 16]) : 0x7fffffff;
      if (__all(v >= target)) break;
      if (++tries > SPIN){
        __hip_atomic_store(abortf, 1, __ATOMIC_RELAXED, __HIP_MEMORY_SCOPE_AGENT);
        out[1] = 55.0f; aborted = 1; break;
      }
      if ((tries & 255) == 0 && ald(abortf) != 0){ aborted = 1; break; }
      __builtin_amdgcn_s_sleep(1);
    }
  }
  if (__syncthreads_or(aborted)) return false;
  return true;
}

// Post S2: drain, add with return; LAST of 32 finishers broadcasts epoch to 32 replica lines.
DEV void postS2(int* s2cnt, int* rep, int t1, int tid){
  asm volatile("s_waitcnt vmcnt(0)" ::: "memory");
  __syncthreads();
  if (tid == 0){
    int old = __hip_atomic_fetch_add(s2cnt, 1, __ATOMIC_RELAXED, __HIP_MEMORY_SCOPE_AGENT);
    if (old == 32 * t1 - 1){
#pragma unroll
      for (int i = 0; i < 32; i++)
        __hip_atomic_store(&rep[i * 16], t1, __ATOMIC_RELAXED, __HIP_MEMORY_SCOPE_AGENT);
    }
  }
}

// Single-lane replica poll (16 readers/line).
DEV bool waitRep(int* repline, int* abortf, int target, int tid, float* out){
  int aborted = 0;
  if (tid == 0){
    int tries = 0;
    while (ald(repline) < target){
      if (++tries > SPIN){
        __hip_atomic_store(abortf, 1, __ATOMIC_RELAXED, __HIP_MEMORY_SCOPE_AGENT);
        out[1] = 55.0f; aborted = 1; break;
      }
      if ((tries & 255) == 0 && ald(abortf) != 0){ aborted = 1; break; }
      __builtin_amdgcn_s_sleep(1);
    }
  }
  if (__syncthreads_or(aborted)) return false;
  return true;
}

// ---------------- persistent decoder ----------------
// 512 blocks x 128 thr; block owns LSTM units j0=2*blk, j1=2*blk+1 (each 8B X-load
// feeds both units' gates -> sc1 op count halved vs 1-unit/block).
// Fence-free protocol as R4: payload via relaxed agent atomics (sc1), flags via
// leaf counters (S1) + counter/replica broadcast (S2). Same post/wait points.
__global__ void __launch_bounds__(NTHR, 2) decoder_kernel(KParams P){
  __shared__ __align__(16) u16 WA16[896 * 16];    // [pair][unit][r][gate] bf16
  __shared__ __align__(16) u16 WD16[1280 * 16];
  __shared__ __align__(16) float SCR[1152];       // [0,1024) partials / stage2 scratch; [1024,1152) gate sums
  __shared__ float HH[32], CATT[32], CDEC[32];    // [unit][batch]
  __shared__ float GBA[8], GBD[8];                // [unit][gate]

  const int blk = blockIdx.x, tid = threadIdx.x;
  int* S1L    = (int*)(P.ws + WS_S1L);
  int* abortf = (int*)(P.ws + WS_ABORT);
  int* S2cnt  = (int*)(P.ws + WS_S2CNT);
  int* S2rep  = (int*)(P.ws + WS_S2REP);
  int* myrep  = &S2rep[(blk & 31) * 16];
  float* ALN = (float*)(P.ws + WS_ALIGN);          // [2][16][200] (att-block-local, plain)
  float* XA  = (float*)(P.ws + WS_XA);             // [2] paired [896][16][2]
  float* XD  = (float*)(P.ws + WS_XD);             // [2] paired [1280][16][2]
  u16*   PM  = (u16*)(P.ws + WS_PM);               // [3200][128] bf16 (const after init)
  float* out = P.out;

  // ---- one-time: stage 2 units' LSTM weights into LDS as bf16 ----
  for (int u = 0; u < 2; u++){
    int j = 2 * blk + u;
#pragma unroll
    for (int g = 0; g < 4; g++){
      const float* rih = P.aih + (size_t)(g * ARNN + j) * 768;
      const float* rhh = P.ahh + (size_t)(g * ARNN + j) * ARNN;
      for (int k = tid; k < KATT; k += NTHR){
        float v = (k < 768) ? rih[k] : rhh[k - 768];
        WA16[(k >> 1) * 16 + u * 8 + (k & 1) * 4 + g] = f2bf(v);
      }
      const float* dih = P.dih + (size_t)(g * ARNN + j) * 1536;
      const float* dhh = P.dhh + (size_t)(g * ARNN + j) * ARNN;
      for (int k = tid; k < KDEC; k += NTHR){
        float v = (k < 1536) ? dih[k] : dhh[k - 1536];
        WD16[(k >> 1) * 16 + u * 8 + (k & 1) * 4 + g] = f2bf(v);
      }
    }
  }
  if (tid < 8){
    int u = tid >> 2, g = tid & 3, j = 2 * blk + u;
    GBA[tid] = P.abi[g * ARNN + j] + P.abh[g * ARNN + j];
    GBD[tid] = P.dbi[g * ARNN + j] + P.dbh[g * ARNN + j];
  }
  if (tid < 32){ CATT[tid] = 0.f; CDEC[tid] = 0.f; }
  if (blk < 16 && tid == 0) ALN[blk * T_ENC] = 1.0f;   // SMA init, parity 0 (block-local)

  // ---- one-time: processed_memory pm[b*200+te][a], published via sc1 u32 stores ----
  for (int rr = 0; rr < 7; rr++){
    int p = blk + rr * NBLK;
    if (p < NB * T_ENC){
      __syncthreads();
      const float4* mrow = (const float4*)(P.memory + (size_t)p * EDIM);
      float4 v = mrow[tid];
      SCR[4 * tid] = v.x; SCR[4 * tid + 1] = v.y;
      SCR[4 * tid + 2] = v.z; SCR[4 * tid + 3] = v.w;
      __syncthreads();
      const float4* w4 = (const float4*)(P.mem_w + (size_t)tid * EDIM);
      float s = 0.f;
      for (int j = 0; j < 128; j++){
        float4 w = w4[j];
        s = fmaf(w.x, SCR[4 * j], s);     s = fmaf(w.y, SCR[4 * j + 1], s);
        s = fmaf(w.z, SCR[4 * j + 2], s); s = fmaf(w.w, SCR[4 * j + 3], s);
      }
      __syncthreads();
      SCR[512 + tid] = s;
      __syncthreads();
      if (tid < 64){
        u32 w2 = (u32)f2bf(SCR[512 + 2 * tid]) | ((u32)f2bf(SCR[512 + 2 * tid + 1]) << 16);
        ast32((u32*)PM + (size_t)p * 64 + tid, w2);
      }
    }
  }

  const int b16 = tid & 15, ks = tid >> 4;   // batch lane, k-slice (8 slices)
  const uint4* WA4 = (const uint4*)WA16;
  const uint4* WD4 = (const uint4*)WD16;

  for (int t = 0; t < T_DEC; t++){
    const int rp = t & 1, wp = rp ^ 1;
    const int t1 = t + 1;
    float* XAr = XA + rp * (KATT * 16);
    float* XAw = XA + wp * (KATT * 16);
    float* XDr = XD + rp * (KDEC * 16);
    float* XDw = XD + wp * (KDEC * 16);

    // ======== stage 1: attention LSTM, units 2blk,2blk+1 ========
    {
      float a00 = 0.f, a01 = 0.f, a02 = 0.f, a03 = 0.f;
      float a10 = 0.f, a11 = 0.f, a12 = 0.f, a13 = 0.f;
      int kp = ks;
#pragma unroll 8
      for (int i = 0; i < 112; i++, kp += 8){
        float x0, x1;
        ald2f(&XAr[kp * 32 + 2 * b16], x0, x1);
        uint4 w0 = WA4[kp * 2 + 0];
        uint4 w1 = WA4[kp * 2 + 1];
        a00 = fmaf(bflo(w0.x), x0, a00); a00 = fmaf(bflo(w0.z), x1, a00);
        a01 = fmaf(bfhi(w0.x), x0, a01); a01 = fmaf(bfhi(w0.z), x1, a01);
        a02 = fmaf(bflo(w0.y), x0, a02); a02 = fmaf(bflo(w0.w), x1, a02);
        a03 = fmaf(bfhi(w0.y), x0, a03); a03 = fmaf(bfhi(w0.w), x1, a03);
        a10 = fmaf(bflo(w1.x), x0, a10); a10 = fmaf(bflo(w1.z), x1, a10);
        a11 = fmaf(bfhi(w1.x), x0, a11); a11 = fmaf(bfhi(w1.z), x1, a11);
        a12 = fmaf(bflo(w1.y), x0, a12); a12 = fmaf(bflo(w1.w), x1, a12);
        a13 = fmaf(bfhi(w1.y), x0, a13); a13 = fmaf(bfhi(w1.w), x1, a13);
      }
      __syncthreads();
      SCR[tid * 8 + 0] = a00; SCR[tid * 8 + 1] = a01;
      SCR[tid * 8 + 2] = a02; SCR[tid * 8 + 3] = a03;
      SCR[tid * 8 + 4] = a10; SCR[tid * 8 + 5] = a11;
      SCR[tid * 8 + 6] = a12; SCR[tid * 8 + 7] = a13;
      __syncthreads();
      {
        int b = tid & 15, u = (tid >> 4) & 1, g = tid >> 5;
        float s = 0.f;
#pragma unroll
        for (int q = 0; q < 8; q++) s += SCR[(q * 16 + b) * 8 + u * 4 + g];
        SCR[1024 + tid] = s;   // GS[b + 16u + 32g]
      }
      __syncthreads();
      if (tid < 32){
        int u = tid >> 4, b = tid & 15, o = 1024 + b + 16 * u;
        float gi = SCR[o]      + GBA[u * 4 + 0];
        float gf = SCR[o + 32] + GBA[u * 4 + 1];
        float gg = SCR[o + 64] + GBA[u * 4 + 2];
        float go = SCR[o + 96] + GBA[u * 4 + 3];
        float cn = fsig(gf) * CATT[tid] + fsig(gi) * ftanh(gg);
        CATT[tid] = cn;
        HH[tid] = fsig(go) * ftanh(cn);
      }
      __syncthreads();
      if (tid < 16){
        ast2f(&XAw[(384 + blk) * 32 + 2 * tid], HH[tid], HH[16 + tid]);  // rows 768+2blk,+1
        ast2f(&XDw[blk * 32 + 2 * tid],        HH[tid], HH[16 + tid]);   // rows 2blk,+1
      }
    }
    postS1(S1L, blk, tid);

    if (blk < 16){
      // ---- attention chain, batch b = blk ----
      if (!waitS1(S1L, abortf, 16 * t1, tid, out)) return;
      const int b = blk;
#pragma unroll 4
      for (int j = tid; j < 512; j += NTHR){       // h_att rows 768..1791, paired
        float h0, h1; ald2f(&XAw[(384 + j) * 32 + 2 * b], h0, h1);
        SCR[2 * j] = h0; SCR[2 * j + 1] = h1;
      }
      __syncthreads();
      float pq = 0.f;
      {
        const float4* q4 = (const float4*)(P.qw + (size_t)tid * ARNN);
        for (int j = 0; j < 256; j++){
          float4 q = q4[j];
          pq = fmaf(q.x, SCR[4 * j], pq);     pq = fmaf(q.y, SCR[4 * j + 1], pq);
          pq = fmaf(q.z, SCR[4 * j + 2], pq); pq = fmaf(q.w, SCR[4 * j + 3], pq);
        }
      }
      __syncthreads();
      SCR[tid] = pq;
      SCR[128 + tid] = P.vw[tid];
      __syncthreads();
#pragma unroll
      for (int pass = 0; pass < 2; pass++){
        int t2 = pass * NTHR + tid;
        if (t2 < T_ENC){
          const u32* pmr = (const u32*)(PM + (size_t)(b * T_ENC + t2) * 128);  // plain (const)
          float e = 0.f;
          for (int a2 = 0; a2 < 64; a2++){
            u32 pv = pmr[a2];
            e = fmaf(SCR[128 + 2 * a2],     ftanh(SCR[2 * a2]     + bflo(pv)), e);
            e = fmaf(SCR[128 + 2 * a2 + 1], ftanh(SCR[2 * a2 + 1] + bfhi(pv)), e);
          }
          SCR[256 + t2] = fsig(e);
        }
      }
      __syncthreads();
      const float* alr = ALN + rp * (NB * T_ENC) + b * T_ENC;   // block-local, plain
      float*       alw = ALN + wp * (NB * T_ENC) + b * T_ENC;
#pragma unroll
      for (int pass = 0; pass < 2; pass++){
        int t2 = pass * NTHR + tid;
        if (t2 < T_ENC){
          float an = alr[t2] * SCR[256 + t2];
          if (t2 > 0) an += alr[t2 - 1] * (1.f - SCR[256 + t2 - 1]);
          SCR[512 + t2] = an;
          alw[t2] = an;
          out[OUT_ALIGN + (size_t)(b * T_DEC + t) * T_ENC + t2] = an;
        }
      }
      __syncthreads();
      {
        const float2* mb = (const float2*)(P.memory + (size_t)b * T_ENC * EDIM);  // plain (const)
        float c0 = 0.f, c1 = 0.f, c2 = 0.f, c3 = 0.f;
        for (int s2 = 0; s2 < T_ENC; s2++){
          float as = SCR[512 + s2];
          float2 m1 = mb[(size_t)s2 * 256 + tid];
          float2 m2 = mb[(size_t)s2 * 256 + tid + 128];
          c0 = fmaf(m1.x, as, c0); c1 = fmaf(m1.y, as, c1);
          c2 = fmaf(m2.x, as, c2); c3 = fmaf(m2.y, as, c3);
        }
        // ctx rows: XA 256+e (pairs 128+tid, 256+tid), XD 1024+e (pairs 512+tid, 640+tid)
        ast2f(&XAw[(128 + tid) * 32 + 2 * b], c0, c1);
        ast2f(&XAw[(256 + tid) * 32 + 2 * b], c2, c3);
        ast2f(&XDw[(512 + tid) * 32 + 2 * b], c0, c1);
        ast2f(&XDw[(640 + tid) * 32 + 2 * b], c2, c3);
      }
      postS2(S2cnt, S2rep, t1, tid);
    } else if (blk < 32){
      // ---- prenet for step t+1: no wait (anti-dep covered transitively: this block
      // passed waitRep(t-1) <= S2(t-1) <= att waited all-S1(t-1) => all stage1(t-1) done) ----
      const int b = blk - 16;
      if (t < T_DEC - 1){
        const int tt = t + 1;
        if (tid < NMEL) SCR[tid] = P.mels[(size_t)(b * NMEL + tid) * T_DEC + t];  // plain (const)
        __syncthreads();
#pragma unroll
        for (int pass = 0; pass < 2; pass++){
          int p2 = pass * NTHR + tid;
          const float* wr = P.pw1 + (size_t)p2 * NMEL;
          float s = 0.f;
          for (int m2 = 0; m2 < NMEL; m2++) s = fmaf(wr[m2], SCR[m2], s);
          s = fmaxf(s, 0.f);
          u32 idx = (u32)((tt * NB + b) * PDIM + p2);
          SCR[384 + p2] = keep_mask(P.k10, P.k11, idx) ? 2.f * s : 0.f;
        }
        __syncthreads();
        {
          const float* w0 = P.pw2 + (size_t)(2 * tid) * PDIM;
          float s0 = 0.f, s1 = 0.f;
          for (int p3 = 0; p3 < PDIM; p3++){
            float xv = SCR[384 + p3];
            s0 = fmaf(w0[p3], xv, s0);
            s1 = fmaf(w0[PDIM + p3], xv, s1);
          }
          s0 = fmaxf(s0, 0.f); s1 = fmaxf(s1, 0.f);
          u32 i0 = (u32)((tt * NB + b) * PDIM + 2 * tid);
          ast2f(&XAw[tid * 32 + 2 * b],
                keep_mask(P.k20, P.k21, i0)      ? 2.f * s0 : 0.f,
                keep_mask(P.k20, P.k21, i0 + 1u) ? 2.f * s1 : 0.f);
        }
      }
      postS2(S2cnt, S2rep, t1, tid);
      // ---- projection(t-1): needs all stage3(t-1) done == all S1 leaves >= 16*t1 ----
      if (t > 0){
        if (!waitS1(S1L, abortf, 16 * t1, tid, out)) return;
#pragma unroll 4
        for (int j = tid; j < 512; j += NTHR){     // h_dec rows 1536.., pairs 768+j
          float h0, h1; ald2f(&XDr[(768 + j) * 32 + 2 * b], h0, h1);
          SCR[2 * j] = h0; SCR[2 * j + 1] = h1;
        }
        __syncthreads();
        float s = 0.f; const float* wr = 0;
        if (tid < 81){
          wr = (tid < 80) ? P.prw + (size_t)tid * 1536 : P.gw;    // plain (const)
          s = (tid < 80) ? P.prb[tid] : P.gb[0];
          for (int k = 0; k < 1024; k++) s = fmaf(wr[k], SCR[k], s);
        }
        __syncthreads();
#pragma unroll 2
        for (int j = tid; j < 256; j += NTHR){     // ctx rows 1024+e, pairs 512+j
          float f0, f1; ald2f(&XDr[(512 + j) * 32 + 2 * b], f0, f1);
          SCR[2 * j] = f0; SCR[2 * j + 1] = f1;
        }
        __syncthreads();
        if (tid < 81){
          for (int e = 0; e < 512; e++) s = fmaf(wr[1024 + e], SCR[e], s);
          if (tid < 80) out[(size_t)(b * NMEL + tid) * T_DEC + (t - 1)] = s;
          else          out[OUT_GATE + (size_t)b * T_DEC + (t - 1)] = s;
        }
        __syncthreads();
      }
    }

    if (!waitRep(myrep, abortf, t1, tid, out)) return;

    // ======== stage 3: decoder LSTM, units 2blk,2blk+1 ========
    {
      float a00 = 0.f, a01 = 0.f, a02 = 0.f, a03 = 0.f;
      float a10 = 0.f, a11 = 0.f, a12 = 0.f, a13 = 0.f;
      int kp = ks;
#pragma unroll 8
      for (int i = 0; i < 96; i++, kp += 8){       // pairs < 768: h_att|ctx (this step)
        float x0, x1;
        ald2f(&XDw[kp * 32 + 2 * b16], x0, x1);
        uint4 w0 = WD4[kp * 2 + 0];
        uint4 w1 = WD4[kp * 2 + 1];
        a00 = fmaf(bflo(w0.x), x0, a00); a00 = fmaf(bflo(w0.z), x1, a00);
        a01 = fmaf(bfhi(w0.x), x0, a01); a01 = fmaf(bfhi(w0.z), x1, a01);
        a02 = fmaf(bflo(w0.y), x0, a02); a02 = fmaf(bflo(w0.w), x1, a02);
        a03 = fmaf(bfhi(w0.y), x0, a03); a03 = fmaf(bfhi(w0.w), x1, a03);
        a10 = fmaf(bflo(w1.x), x0, a10); a10 = fmaf(bflo(w1.z), x1, a10);
        a11 = fmaf(bfhi(w1.x), x0, a11); a11 = fmaf(bfhi(w1.z), x1, a11);
        a12 = fmaf(bflo(w1.y), x0, a12); a12 = fmaf(bflo(w1.w), x1, a12);
        a13 = fmaf(bfhi(w1.y), x0, a13); a13 = fmaf(bfhi(w1.w), x1, a13);
      }
#pragma unroll 8
      for (int i = 0; i < 64; i++, kp += 8){       // pairs >= 768: h_dec (prev step)
        float x0, x1;
        ald2f(&XDr[kp * 32 + 2 * b16], x0, x1);
        uint4 w0 = WD4[kp * 2 + 0];
        uint4 w1 = WD4[kp * 2 + 1];
        a00 = fmaf(bflo(w0.x), x0, a00); a00 = fmaf(bflo(w0.z), x1, a00);
        a01 = fmaf(bfhi(w0.x), x0, a01); a01 = fmaf(bfhi(w0.z), x1, a01);
        a02 = fmaf(bflo(w0.y), x0, a02); a02 = fmaf(bflo(w0.w), x1, a02);
        a03 = fmaf(bfhi(w0.y), x0, a03); a03 = fmaf(bfhi(w0.w), x1, a03);
        a10 = fmaf(bflo(w1.x), x0, a10); a10 = fmaf(bflo(w1.z), x1, a10);
        a11 = fmaf(bfhi(w1.x), x0, a11); a11 = fmaf(bfhi(w1.z), x1, a11);
        a12 = fmaf(bflo(w1.y), x0, a12); a12 = fmaf(bflo(w1.w), x1, a12);
        a13 = fmaf(bfhi(w1.y), x0, a13); a13 = fmaf(bfhi(w1.w), x1, a13);
      }
      __syncthreads();
      SCR[tid * 8 + 0] = a00; SCR[tid * 8 + 1] = a01;
      SCR[tid * 8 + 2] = a02; SCR[tid * 8 + 3] = a03;
      SCR[tid * 8 + 4] = a10; SCR[tid * 8 + 5] = a11;
      SCR[tid * 8 + 6] = a12; SCR[tid * 8 + 7] = a13;
      __syncthreads();
      {
        int b = tid & 15, u = (tid >> 4) & 1, g = tid >> 5;
        float s = 0.f;
#pragma unroll
        for (int q = 0; q < 8; q++) s += SCR[(q * 16 + b) * 8 + u * 4 + g];
        SCR[1024 + tid] = s;
      }
      __syncthreads();
      if (tid < 32){
        int u = tid >> 4, b = tid & 15, o = 1024 + b + 16 * u;
        float gi = SCR[o]      + GBD[u * 4 + 0];
        float gf = SCR[o + 32] + GBD[u * 4 + 1];
        float gg = SCR[o + 64] + GBD[u * 4 + 2];
        float go = SCR[o + 96] + GBD[u * 4 + 3];
        float cn = fsig(gf) * CDEC[tid] + fsig(gi) * ftanh(gg);
        CDEC[tid] = cn;
        HH[tid] = fsig(go) * ftanh(cn);
      }
      __syncthreads();
      if (tid < 16)
        ast2f(&XDw[(768 + blk) * 32 + 2 * tid], HH[tid], HH[16 + tid]);  // rows 1536+2blk,+1
    }
    // stage3's h stores drained by next iteration's postS1 vmcnt(0).
  }

  // ---- epilogue: final S1 post, then projection for t = 299 (parity 0) ----
  postS1(S1L, blk, tid);
  if (blk >= 16 && blk < 32){
    if (!waitS1(S1L, abortf, 16 * (T_DEC + 1), tid, out)) return;
    const int b = blk - 16;
    const float* XD0 = XD;   // parity 0
#pragma unroll 4
    for (int j = tid; j < 512; j += NTHR){
      float h0, h1; ald2f(&XD0[(768 + j) * 32 + 2 * b], h0, h1);
      SCR[2 * j] = h0; SCR[2 * j + 1] = h1;
    }
    __syncthreads();
    float s = 0.f; const float* wr = 0;
    if (tid < 81){
      wr = (tid < 80) ? P.prw + (size_t)tid * 1536 : P.gw;
      s = (tid < 80) ? P.prb[tid] : P.gb[0];
      for (int k = 0; k < 1024; k++) s = fmaf(wr[k], SCR[k], s);
    }
    __syncthreads();
#pragma unroll 2
    for (int j = tid; j < 256; j += NTHR){
      float f0, f1; ald2f(&XD0[(512 + j) * 32 + 2 * b], f0, f1);
      SCR[2 * j] = f0; SCR[2 * j + 1] = f1;
    }
    __syncthreads();
    if (tid < 81){
      for (int e = 0; e < 512; e++) s = fmaf(wr[1024 + e], SCR[e], s);
      if (tid < 80) out[(size_t)(b * NMEL + tid) * T_DEC + (T_DEC - 1)] = s;
      else          out[OUT_GATE + (size_t)b * T_DEC + (T_DEC - 1)] = s;
    }
  }
}

// ---------------- launch ----------------
extern "C" void kernel_launch(void* const* d_in, const int* in_sizes, int n_in,
                              void* d_out, int out_size, void* d_ws, size_t ws_size,
                              hipStream_t stream){
  if (ws_size < (size_t)WS_END){
    hipLaunchKernelGGL(sentinel_kernel, dim3(1), dim3(64), 0, stream, (float*)d_out);
    return;
  }
  hipMemsetAsync(d_ws, 0, (size_t)WS_ZERO, stream);

  KParams P;
  P.memory = (const float*)d_in[0];  P.mels = (const float*)d_in[1];
  P.pw1 = (const float*)d_in[2];     P.pw2 = (const float*)d_in[3];
  P.mem_w = (const float*)d_in[4];   P.qw = (const float*)d_in[5];
  P.vw = (const float*)d_in[6];
  P.aih = (const float*)d_in[7];     P.ahh = (const float*)d_in[8];
  P.abi = (const float*)d_in[9];     P.abh = (const float*)d_in[10];
  P.dih = (const float*)d_in[11];    P.dhh = (const float*)d_in[12];
  P.dbi = (const float*)d_in[13];    P.dbh = (const float*)d_in[14];
  P.prw = (const float*)d_in[15];    P.prb = (const float*)d_in[16];
  P.gw = (const float*)d_in[17];     P.gb = (const float*)d_in[18];
  P.ws = (char*)d_ws; P.out = (float*)d_out;
  tf2x32(0u, 42u, 0u, 0u, P.k10, P.k11);
  tf2x32(0u, 42u, 0u, 1u, P.k20, P.k21);

  hipLaunchKernelGGL(decoder_kernel, dim3(NBLK), dim3(NTHR), 0, stream, P);
}

// Round 6
// 24790.268 us; speedup vs baseline: 1.4810x; 1.4810x over previous
//
#include <hip/hip_runtime.h>

typedef unsigned int u32;
typedef unsigned short u16;
typedef unsigned long long u64;
#define DEV __device__ __forceinline__

// ---------------- sizes ----------------
#define T_DEC 300
#define NB    16
#define T_ENC 200
#define EDIM  512
#define ARNN  1024
#define PDIM  256
#define ADIM  128
#define NMEL  80
#define KATT  1792            // 256 prenet + 512 ctx + 1024 h_att (448 quads)
#define KDEC  2560            // 1024 h_att + 512 ctx + 1024 h_dec (640 quads)
#define NBLK  1024            // back to R4 geometry: 1 unit/block, 4 blocks/CU
#define NTHR  128
#define SPIN  2000000         // poll-iteration limit

// ---------------- ws byte offsets ----------------
// counters page: S1 leaves[32] @0 (stride 64B), abort @2048, S2cnt @2112,
// S2rep[32] @2560 (stride 64B)
#define WS_S1L    0
#define WS_ABORT  2048
#define WS_S2CNT  2112
#define WS_S2REP  2560
#define WS_ALIGN  4608                      // f32 [2][16][200] = 25600 (att-block-local)
#define WS_XA     30208                     // f32 [2][448][16][4] quads = 229376
#define WS_XD     259584                    // f32 [2][640][16][4] quads = 327680
#define WS_PM     587264                    // u16 [3200][128] = 819200
#define WS_END    1406464
#define WS_ZERO   587264

// quad layout: element (k,b) at float offset (k>>2)*64 + b*4 + (k&3)

// ---------------- out layout (f32 elements) ----------------
#define OUT_GATE  (NB*NMEL*T_DEC)           // 384000
#define OUT_ALIGN (OUT_GATE + NB*T_DEC)     // 388800

// ---------------- helpers ----------------
DEV float bflo(u32 u){ return __uint_as_float(u << 16); }
DEV float bfhi(u32 u){ return __uint_as_float(u & 0xffff0000u); }
DEV u16 f2bf(float f){
  u32 u = __float_as_uint(f);
  return (u16)((u + 0x7fffu + ((u >> 16) & 1u)) >> 16);
}
DEV float fsig(float x){ return 1.0f / (1.0f + __expf(-x)); }
DEV float ftanh(float x){
  float xx = fminf(15.0f, fmaxf(-15.0f, x));
  float e = __expf(2.0f * xx);
  return (e - 1.0f) / (e + 1.0f);
}

// ---- coherence-point accessors: sc0 sc1 ops bypass L1/L2, meet at coherence point ----
DEV void ast (float* p, float v){ __hip_atomic_store(p, v, __ATOMIC_RELAXED, __HIP_MEMORY_SCOPE_AGENT); }
DEV void ast32(u32* p, u32 v)  { __hip_atomic_store(p, v, __ATOMIC_RELAXED, __HIP_MEMORY_SCOPE_AGENT); }
DEV int  ald (const int* p)    { return __hip_atomic_load(p, __ATOMIC_RELAXED, __HIP_MEMORY_SCOPE_AGENT); }
DEV void ald2f(const float* p, float& f0, float& f1){
  u64 v = __hip_atomic_load((const u64*)p, __ATOMIC_RELAXED, __HIP_MEMORY_SCOPE_AGENT);
  f0 = __uint_as_float((u32)v);
  f1 = __uint_as_float((u32)(v >> 32));
}
DEV void ast2f(float* p, float f0, float f1){
  u64 v = (u64)__float_as_uint(f0) | ((u64)__float_as_uint(f1) << 32);
  __hip_atomic_store((u64*)p, v, __ATOMIC_RELAXED, __HIP_MEMORY_SCOPE_AGENT);
}
// wide coherent load: 16B, same sc0 sc1 policy as the agent atomics, but one op.
// NOTE: result NOT ready until an explicit s_waitcnt vmcnt — callers pipeline manually.
DEV void ld16(float4& d, const float* p){
  asm volatile("global_load_dwordx4 %0, %1, off sc0 sc1" : "=v"(d) : "v"(p) : "memory");
}

// ---------------- Threefry-2x32-20 (JAX partitionable; R3/R7-verified) ----------------
__host__ __device__ inline void tf2x32(u32 k0, u32 k1, u32 x0, u32 x1, u32& o0, u32& o1){
  u32 k2 = k0 ^ k1 ^ 0x1BD11BDAu;
  x0 += k0; x1 += k1;
#define TFR(r) { x0 += x1; x1 = (x1 << r) | (x1 >> (32 - r)); x1 ^= x0; }
  TFR(13) TFR(15) TFR(26) TFR(6)  x0 += k1; x1 += k2 + 1u;
  TFR(17) TFR(29) TFR(16) TFR(24) x0 += k2; x1 += k0 + 2u;
  TFR(13) TFR(15) TFR(26) TFR(6)  x0 += k0; x1 += k1 + 3u;
  TFR(17) TFR(29) TFR(16) TFR(24) x0 += k1; x1 += k2 + 4u;
  TFR(13) TFR(15) TFR(26) TFR(6)  x0 += k2; x1 += k0 + 5u;
#undef TFR
  o0 = x0; o1 = x1;
}
DEV bool keep_mask(u32 k0, u32 k1, u32 idx){
  u32 a, b; tf2x32(k0, k1, 0u, idx, a, b);
  return (((a ^ b) >> 31) & 1u) == 0u;
}

// ---------------- params ----------------
struct KParams {
  const float *memory, *mels, *pw1, *pw2, *mem_w, *qw, *vw;
  const float *aih, *ahh, *abi, *abh, *dih, *dhh, *dbi, *dbh;
  const float *prw, *prb, *gw, *gb;
  char* ws; float* out;
  u32 k10, k11, k20, k21;
};

__global__ void sentinel_kernel(float* out){ if (threadIdx.x == 0) out[0] = 123.0f; }

// ---------------- sync primitives (fence-free) ----------------
// 32 S1 leaves, 32 blocks each: parallel across cachelines, <=32 serialized RMWs/line.
DEV void postS1(int* S1L, int blk, int tid){
  asm volatile("s_waitcnt vmcnt(0)" ::: "memory");
  __syncthreads();
  if (tid == 0)
    (void)__hip_atomic_fetch_add(&S1L[(blk >> 5) * 16], 1, __ATOMIC_RELAXED, __HIP_MEMORY_SCOPE_AGENT);
}

DEV bool waitS1(int* S1L, int* abortf, int target, int tid, float* out){
  int aborted = 0;
  if (tid < 64){
    int tries = 0;
    for (;;){
      int v = (tid < 32) ? ald(&S1L[tid * 16]) : 0x7fffffff;
      if (__all(v >= target)) break;
      if (++tries > SPIN){
        __hip_atomic_store(abortf, 1, __ATOMIC_RELAXED, __HIP_MEMORY_SCOPE_AGENT);
        out[1] = 55.0f; aborted = 1; break;
      }
      if ((tries & 255) == 0 && ald(abortf) != 0){ aborted = 1; break; }
      __builtin_amdgcn_s_sleep(1);
    }
  }
  if (__syncthreads_or(aborted)) return false;
  return true;
}

DEV void postS2(int* s2cnt, int* rep, int t1, int tid){
  asm volatile("s_waitcnt vmcnt(0)" ::: "memory");
  __syncthreads();
  if (tid == 0){
    int old = __hip_atomic_fetch_add(s2cnt, 1, __ATOMIC_RELAXED, __HIP_MEMORY_SCOPE_AGENT);
    if (old == 32 * t1 - 1){
#pragma unroll
      for (int i = 0; i < 32; i++)
        __hip_atomic_store(&rep[i * 16], t1, __ATOMIC_RELAXED, __HIP_MEMORY_SCOPE_AGENT);
    }
  }
}

DEV bool waitRep(int* repline, int* abortf, int target, int tid, float* out){
  int aborted = 0;
  if (tid == 0){
    int tries = 0;
    while (ald(repline) < target){
      if (++tries > SPIN){
        __hip_atomic_store(abortf, 1, __ATOMIC_RELAXED, __HIP_MEMORY_SCOPE_AGENT);
        out[1] = 55.0f; aborted = 1; break;
      }
      if ((tries & 255) == 0 && ald(abortf) != 0){ aborted = 1; break; }
      __builtin_amdgcn_s_sleep(1);
    }
  }
  if (__syncthreads_or(aborted)) return false;
  return true;
}

// ---------------- persistent decoder ----------------
// R4 geometry (1024 blocks x 128 thr, 1 unit/block, 4 blocks/CU) + quad X layout:
// LSTM main loops read X via 16B coherent loads (ld16), software-pipelined 2-deep
// with counted vmcnt(8) + sched_barrier. Producers keep 4/8B relaxed-atomic stores.
__global__ void __launch_bounds__(NTHR, 2) decoder_kernel(KParams P){
  __shared__ __align__(16) u16 WA[KATT * 4];   // [k][gate] bf16 att weights
  __shared__ __align__(16) u16 WD[KDEC * 4];   // [k][gate] bf16 dec weights
  __shared__ __align__(16) float SCR[1024];
  __shared__ float CATT[16], CDEC[16];
  __shared__ float GBA[4], GBD[4];

  const int blk = blockIdx.x, tid = threadIdx.x;
  int* S1L    = (int*)(P.ws + WS_S1L);
  int* abortf = (int*)(P.ws + WS_ABORT);
  int* S2cnt  = (int*)(P.ws + WS_S2CNT);
  int* S2rep  = (int*)(P.ws + WS_S2REP);
  int* myrep  = &S2rep[(blk & 31) * 16];
  float* ALN = (float*)(P.ws + WS_ALIGN);          // [2][16][200] (att-block-local, plain)
  float* XA  = (float*)(P.ws + WS_XA);             // [2] quads [448][16][4]
  float* XD  = (float*)(P.ws + WS_XD);             // [2] quads [640][16][4]
  u16*   PM  = (u16*)(P.ws + WS_PM);               // [3200][128] bf16 (const after init)
  float* out = P.out;

  // ---- one-time: stage this block's LSTM-unit weights into LDS as bf16 ----
#pragma unroll
  for (int g = 0; g < 4; g++){
    const float* rih = P.aih + (size_t)(g * ARNN + blk) * 768;
    for (int k = tid; k < 768; k += NTHR)  WA[k * 4 + g] = f2bf(rih[k]);
    const float* rhh = P.ahh + (size_t)(g * ARNN + blk) * ARNN;
    for (int k = tid; k < ARNN; k += NTHR) WA[(768 + k) * 4 + g] = f2bf(rhh[k]);
    const float* dih = P.dih + (size_t)(g * ARNN + blk) * 1536;
    for (int k = tid; k < 1536; k += NTHR) WD[k * 4 + g] = f2bf(dih[k]);
    const float* dhh = P.dhh + (size_t)(g * ARNN + blk) * ARNN;
    for (int k = tid; k < ARNN; k += NTHR) WD[(1536 + k) * 4 + g] = f2bf(dhh[k]);
  }
  if (tid < 4){
    GBA[tid] = P.abi[tid * ARNN + blk] + P.abh[tid * ARNN + blk];
    GBD[tid] = P.dbi[tid * ARNN + blk] + P.dbh[tid * ARNN + blk];
  }
  if (tid < 16){ CATT[tid] = 0.f; CDEC[tid] = 0.f; }
  if (blk < 16 && tid == 0) ALN[blk * T_ENC] = 1.0f;   // SMA init, parity 0 (block-local)

  // ---- one-time: processed_memory pm[b*200+te][a], published via sc1 u32 stores ----
  for (int rr = 0; rr < 4; rr++){
    int p = blk + rr * NBLK;
    if (p < NB * T_ENC){
      __syncthreads();
      const float4* mrow = (const float4*)(P.memory + (size_t)p * EDIM);
      float4 v = mrow[tid];
      SCR[4 * tid] = v.x; SCR[4 * tid + 1] = v.y;
      SCR[4 * tid + 2] = v.z; SCR[4 * tid + 3] = v.w;
      __syncthreads();
      const float4* w4 = (const float4*)(P.mem_w + (size_t)tid * EDIM);
      float s = 0.f;
      for (int j = 0; j < 128; j++){
        float4 w = w4[j];
        s = fmaf(w.x, SCR[4 * j], s);     s = fmaf(w.y, SCR[4 * j + 1], s);
        s = fmaf(w.z, SCR[4 * j + 2], s); s = fmaf(w.w, SCR[4 * j + 3], s);
      }
      __syncthreads();
      SCR[512 + tid] = s;
      __syncthreads();
      if (tid < 64){
        u32 w2 = (u32)f2bf(SCR[512 + 2 * tid]) | ((u32)f2bf(SCR[512 + 2 * tid + 1]) << 16);
        ast32((u32*)PM + (size_t)p * 64 + tid, w2);
      }
    }
  }

  const int b16 = tid & 15, ks = tid >> 4;   // batch lane, quad-slice (8 slices)
  const uint4* WA4 = (const uint4*)WA;       // quad q -> WA4[2q], WA4[2q+1]
  const uint4* WD4 = (const uint4*)WD;

#define CONSUME(Wp, Xv, qc)                                                        \
  { float4 x_ = (Xv);                                                              \
    uint4 w01 = (Wp)[(qc) * 2], w23 = (Wp)[(qc) * 2 + 1];                          \
    a0 = fmaf(bflo(w01.x), x_.x, a0); a0 = fmaf(bflo(w01.z), x_.y, a0);            \
    a0 = fmaf(bflo(w23.x), x_.z, a0); a0 = fmaf(bflo(w23.z), x_.w, a0);            \
    a1 = fmaf(bfhi(w01.x), x_.x, a1); a1 = fmaf(bfhi(w01.z), x_.y, a1);            \
    a1 = fmaf(bfhi(w23.x), x_.z, a1); a1 = fmaf(bfhi(w23.z), x_.w, a1);            \
    a2 = fmaf(bflo(w01.y), x_.x, a2); a2 = fmaf(bflo(w01.w), x_.y, a2);            \
    a2 = fmaf(bflo(w23.y), x_.z, a2); a2 = fmaf(bflo(w23.w), x_.w, a2);            \
    a3 = fmaf(bfhi(w01.y), x_.x, a3); a3 = fmaf(bfhi(w01.w), x_.y, a3);            \
    a3 = fmaf(bfhi(w23.y), x_.z, a3); a3 = fmaf(bfhi(w23.w), x_.w, a3); }

  for (int t = 0; t < T_DEC; t++){
    const int rp = t & 1, wp = rp ^ 1;
    const int t1 = t + 1;
    float* XAr = XA + rp * (KATT * 16);
    float* XAw = XA + wp * (KATT * 16);
    float* XDr = XD + rp * (KDEC * 16);
    float* XDw = XD + wp * (KDEC * 16);

    // ======== stage 1: attention LSTM, unit blk — 56 quads, 7 groups of 8, 2-deep ========
    {
      float a0 = 0.f, a1 = 0.f, a2 = 0.f, a3 = 0.f;
      const float* xb = XAr + b16 * 4;
      float4 X0[8], X1[8];
      asm volatile("s_waitcnt vmcnt(0)" ::: "memory");   // only our loads counted below
#pragma unroll
      for (int j = 0; j < 8; j++) ld16(X0[j], xb + (ks + 8 * j) * 64);
#pragma unroll
      for (int g = 0; g < 7; g++){
        float4* C = (g & 1) ? X1 : X0;
        float4* N = (g & 1) ? X0 : X1;
        if (g < 6){
#pragma unroll
          for (int j = 0; j < 8; j++) ld16(N[j], xb + (ks + 8 * (8 * (g + 1) + j)) * 64);
          asm volatile("s_waitcnt vmcnt(8)" ::: "memory");
        } else {
          asm volatile("s_waitcnt vmcnt(0)" ::: "memory");
        }
        __builtin_amdgcn_sched_barrier(0);
#pragma unroll
        for (int j = 0; j < 8; j++) CONSUME(WA4, C[j], ks + 8 * (8 * g + j));
      }
      __syncthreads();
      SCR[tid * 4 + 0] = a0; SCR[tid * 4 + 1] = a1;
      SCR[tid * 4 + 2] = a2; SCR[tid * 4 + 3] = a3;
      __syncthreads();
      if (tid < 64){
        int g = tid >> 4, bb = tid & 15;
        float s = 0.f;
#pragma unroll
        for (int q = 0; q < 8; q++) s += SCR[q * 64 + bb * 4 + g];
        SCR[512 + g * 16 + bb] = s;
      }
      __syncthreads();
      if (tid < 16){
        float gi = SCR[512 + tid] + GBA[0];
        float gf = SCR[528 + tid] + GBA[1];
        float gg = SCR[544 + tid] + GBA[2];
        float go = SCR[560 + tid] + GBA[3];
        float cn = fsig(gf) * CATT[tid] + fsig(gi) * ftanh(gg);
        CATT[tid] = cn;
        float h = fsig(go) * ftanh(cn);
        // row 768+blk -> quad 192+(blk>>2), pos blk&3 ; XD row blk -> quad blk>>2
        ast(&XAw[(192 + (blk >> 2)) * 64 + tid * 4 + (blk & 3)], h);
        ast(&XDw[(blk >> 2) * 64 + tid * 4 + (blk & 3)], h);
      }
    }
    postS1(S1L, blk, tid);

    if (blk < 16){
      // ---- attention chain, batch b = blk ----
      if (!waitS1(S1L, abortf, 32 * t1, tid, out)) return;
      const int b = blk;
      for (int j = tid; j < 256; j += NTHR){       // h_att quads 192..447
        const float* qa = XAw + (192 + j) * 64 + b * 4;
        float h0, h1, h2, h3;
        ald2f(qa, h0, h1); ald2f(qa + 2, h2, h3);
        SCR[4 * j] = h0; SCR[4 * j + 1] = h1; SCR[4 * j + 2] = h2; SCR[4 * j + 3] = h3;
      }
      __syncthreads();
      float pq = 0.f;
      {
        const float4* q4 = (const float4*)(P.qw + (size_t)tid * ARNN);
        for (int j = 0; j < 256; j++){
          float4 q = q4[j];
          pq = fmaf(q.x, SCR[4 * j], pq);     pq = fmaf(q.y, SCR[4 * j + 1], pq);
          pq = fmaf(q.z, SCR[4 * j + 2], pq); pq = fmaf(q.w, SCR[4 * j + 3], pq);
        }
      }
      __syncthreads();
      SCR[tid] = pq;
      SCR[128 + tid] = P.vw[tid];
      __syncthreads();
#pragma unroll
      for (int pass = 0; pass < 2; pass++){
        int t2 = pass * NTHR + tid;
        if (t2 < T_ENC){
          const u32* pmr = (const u32*)(PM + (size_t)(b * T_ENC + t2) * 128);  // plain (const)
          float e = 0.f;
          for (int a2 = 0; a2 < 64; a2++){
            u32 pv = pmr[a2];
            e = fmaf(SCR[128 + 2 * a2],     ftanh(SCR[2 * a2]     + bflo(pv)), e);
            e = fmaf(SCR[128 + 2 * a2 + 1], ftanh(SCR[2 * a2 + 1] + bfhi(pv)), e);
          }
          SCR[256 + t2] = fsig(e);
        }
      }
      __syncthreads();
      const float* alr = ALN + rp * (NB * T_ENC) + b * T_ENC;   // block-local, plain
      float*       alw = ALN + wp * (NB * T_ENC) + b * T_ENC;
#pragma unroll
      for (int pass = 0; pass < 2; pass++){
        int t2 = pass * NTHR + tid;
        if (t2 < T_ENC){
          float an = alr[t2] * SCR[256 + t2];
          if (t2 > 0) an += alr[t2 - 1] * (1.f - SCR[256 + t2 - 1]);
          SCR[512 + t2] = an;
          alw[t2] = an;
          out[OUT_ALIGN + (size_t)(b * T_DEC + t) * T_ENC + t2] = an;
        }
      }
      __syncthreads();
      {
        const float2* mb = (const float2*)(P.memory + (size_t)b * T_ENC * EDIM);  // plain (const)
        float c0 = 0.f, c1 = 0.f, c2 = 0.f, c3 = 0.f;
        for (int s2 = 0; s2 < T_ENC; s2++){
          float as = SCR[512 + s2];
          float2 m1 = mb[(size_t)s2 * 256 + tid];
          float2 m2 = mb[(size_t)s2 * 256 + tid + 128];
          c0 = fmaf(m1.x, as, c0); c1 = fmaf(m1.y, as, c1);
          c2 = fmaf(m2.x, as, c2); c3 = fmaf(m2.y, as, c3);
        }
        // ctx e0=2tid (rows 256+2tid | XD 1024+2tid), e1=2tid+256 (rows 512+2tid | XD 1280+2tid)
        int qh = tid >> 1, pos = 2 * (tid & 1);
        ast2f(&XAw[(64  + qh) * 64 + b * 4 + pos], c0, c1);
        ast2f(&XAw[(128 + qh) * 64 + b * 4 + pos], c2, c3);
        ast2f(&XDw[(256 + qh) * 64 + b * 4 + pos], c0, c1);
        ast2f(&XDw[(320 + qh) * 64 + b * 4 + pos], c2, c3);
      }
      postS2(S2cnt, S2rep, t1, tid);
    } else if (blk < 32){
      // ---- prenet for step t+1: no wait (anti-dep covered by prior waitRep) ----
      const int b = blk - 16;
      if (t < T_DEC - 1){
        const int tt = t + 1;
        if (tid < NMEL) SCR[tid] = P.mels[(size_t)(b * NMEL + tid) * T_DEC + t];  // plain (const)
        __syncthreads();
#pragma unroll
        for (int pass = 0; pass < 2; pass++){
          int p2 = pass * NTHR + tid;
          const float* wr = P.pw1 + (size_t)p2 * NMEL;
          float s = 0.f;
          for (int m2 = 0; m2 < NMEL; m2++) s = fmaf(wr[m2], SCR[m2], s);
          s = fmaxf(s, 0.f);
          u32 idx = (u32)((tt * NB + b) * PDIM + p2);
          SCR[384 + p2] = keep_mask(P.k10, P.k11, idx) ? 2.f * s : 0.f;
        }
        __syncthreads();
        {
          const float* w0 = P.pw2 + (size_t)(2 * tid) * PDIM;
          float s0 = 0.f, s1 = 0.f;
          for (int p3 = 0; p3 < PDIM; p3++){
            float xv = SCR[384 + p3];
            s0 = fmaf(w0[p3], xv, s0);
            s1 = fmaf(w0[PDIM + p3], xv, s1);
          }
          s0 = fmaxf(s0, 0.f); s1 = fmaxf(s1, 0.f);
          u32 i0 = (u32)((tt * NB + b) * PDIM + 2 * tid);
          // rows 2tid,2tid+1 -> quad tid>>1, pos 2*(tid&1)
          ast2f(&XAw[(tid >> 1) * 64 + b * 4 + 2 * (tid & 1)],
                keep_mask(P.k20, P.k21, i0)      ? 2.f * s0 : 0.f,
                keep_mask(P.k20, P.k21, i0 + 1u) ? 2.f * s1 : 0.f);
        }
      }
      postS2(S2cnt, S2rep, t1, tid);
      // ---- projection(t-1): needs all stage3(t-1) done == all S1 leaves >= 32*t1 ----
      if (t > 0){
        if (!waitS1(S1L, abortf, 32 * t1, tid, out)) return;
        for (int j = tid; j < 256; j += NTHR){     // h_dec quads 384..639
          const float* qa = XDr + (384 + j) * 64 + b * 4;
          float h0, h1, h2, h3;
          ald2f(qa, h0, h1); ald2f(qa + 2, h2, h3);
          SCR[4 * j] = h0; SCR[4 * j + 1] = h1; SCR[4 * j + 2] = h2; SCR[4 * j + 3] = h3;
        }
        __syncthreads();
        float s = 0.f; const float* wr = 0;
        if (tid < 81){
          wr = (tid < 80) ? P.prw + (size_t)tid * 1536 : P.gw;    // plain (const)
          s = (tid < 80) ? P.prb[tid] : P.gb[0];
          for (int k = 0; k < 1024; k++) s = fmaf(wr[k], SCR[k], s);
        }
        __syncthreads();
        for (int j = tid; j < 128; j += NTHR){     // ctx quads 256..383
          const float* qa = XDr + (256 + j) * 64 + b * 4;
          float f0, f1, f2, f3;
          ald2f(qa, f0, f1); ald2f(qa + 2, f2, f3);
          SCR[4 * j] = f0; SCR[4 * j + 1] = f1; SCR[4 * j + 2] = f2; SCR[4 * j + 3] = f3;
        }
        __syncthreads();
        if (tid < 81){
          for (int e = 0; e < 512; e++) s = fmaf(wr[1024 + e], SCR[e], s);
          if (tid < 80) out[(size_t)(b * NMEL + tid) * T_DEC + (t - 1)] = s;
          else          out[OUT_GATE + (size_t)b * T_DEC + (t - 1)] = s;
        }
        __syncthreads();
      }
    }

    if (!waitRep(myrep, abortf, t1, tid, out)) return;

    // ======== stage 3: decoder LSTM, unit blk — 80 quads, 10 groups; 0-5 XDw, 6-9 XDr ========
    {
      float a0 = 0.f, a1 = 0.f, a2 = 0.f, a3 = 0.f;
      const float* xw = XDw + b16 * 4;
      const float* xr = XDr + b16 * 4;
      float4 X0[8], X1[8];
      asm volatile("s_waitcnt vmcnt(0)" ::: "memory");
#pragma unroll
      for (int j = 0; j < 8; j++) ld16(X0[j], xw + (ks + 8 * j) * 64);
#pragma unroll
      for (int g = 0; g < 10; g++){
        float4* C = (g & 1) ? X1 : X0;
        float4* N = (g & 1) ? X0 : X1;
        if (g < 9){
          const float* src = (g + 1 < 6) ? xw : xr;    // quads >=384 live in XDr
#pragma unroll
          for (int j = 0; j < 8; j++) ld16(N[j], src + (ks + 8 * (8 * (g + 1) + j)) * 64);
          asm volatile("s_waitcnt vmcnt(8)" ::: "memory");
        } else {
          asm volatile("s_waitcnt vmcnt(0)" ::: "memory");
        }
        __builtin_amdgcn_sched_barrier(0);
#pragma unroll
        for (int j = 0; j < 8; j++) CONSUME(WD4, C[j], ks + 8 * (8 * g + j));
      }
      __syncthreads();
      SCR[tid * 4 + 0] = a0; SCR[tid * 4 + 1] = a1;
      SCR[tid * 4 + 2] = a2; SCR[tid * 4 + 3] = a3;
      __syncthreads();
      if (tid < 64){
        int g = tid >> 4, bb = tid & 15;
        float s = 0.f;
#pragma unroll
        for (int q = 0; q < 8; q++) s += SCR[q * 64 + bb * 4 + g];
        SCR[512 + g * 16 + bb] = s;
      }
      __syncthreads();
      if (tid < 16){
        float gi = SCR[512 + tid] + GBD[0];
        float gf = SCR[528 + tid] + GBD[1];
        float gg = SCR[544 + tid] + GBD[2];
        float go = SCR[560 + tid] + GBD[3];
        float cn = fsig(gf) * CDEC[tid] + fsig(gi) * ftanh(gg);
        CDEC[tid] = cn;
        float h = fsig(go) * ftanh(cn);
        // row 1536+blk -> quad 384+(blk>>2), pos blk&3
        ast(&XDw[(384 + (blk >> 2)) * 64 + tid * 4 + (blk & 3)], h);
      }
    }
    // stage3's h stores drained by next iteration's postS1 vmcnt(0).
  }

  // ---- epilogue: final S1 post, then projection for t = 299 (parity 0) ----
  postS1(S1L, blk, tid);
  if (blk >= 16 && blk < 32){
    if (!waitS1(S1L, abortf, 32 * (T_DEC + 1), tid, out)) return;
    const int b = blk - 16;
    const float* XD0 = XD;   // parity 0
    for (int j = tid; j < 256; j += NTHR){
      const float* qa = XD0 + (384 + j) * 64 + b * 4;
      float h0, h1, h2, h3;
      ald2f(qa, h0, h1); ald2f(qa + 2, h2, h3);
      SCR[4 * j] = h0; SCR[4 * j + 1] = h1; SCR[4 * j + 2] = h2; SCR[4 * j + 3] = h3;
    }
    __syncthreads();
    float s = 0.f; const float* wr = 0;
    if (tid < 81){
      wr = (tid < 80) ? P.prw + (size_t)tid * 1536 : P.gw;
      s = (tid < 80) ? P.prb[tid] : P.gb[0];
      for (int k = 0; k < 1024; k++) s = fmaf(wr[k], SCR[k], s);
    }
    __syncthreads();
    for (int j = tid; j < 128; j += NTHR){
      const float* qa = XD0 + (256 + j) * 64 + b * 4;
      float f0, f1, f2, f3;
      ald2f(qa, f0, f1); ald2f(qa + 2, f2, f3);
      SCR[4 * j] = f0; SCR[4 * j + 1] = f1; SCR[4 * j + 2] = f2; SCR[4 * j + 3] = f3;
    }
    __syncthreads();
    if (tid < 81){
      for (int e = 0; e < 512; e++) s = fmaf(wr[1024 + e], SCR[e], s);
      if (tid < 80) out[(size_t)(b * NMEL + tid) * T_DEC + (T_DEC - 1)] = s;
      else          out[OUT_GATE + (size_t)b * T_DEC + (T_DEC - 1)] = s;
    }
  }
}

// ---------------- launch ----------------
extern "C" void kernel_launch(void* const* d_in, const int* in_sizes, int n_in,
                              void* d_out, int out_size, void* d_ws, size_t ws_size,
                              hipStream_t stream){
  if (ws_size < (size_t)WS_END){
    hipLaunchKernelGGL(sentinel_kernel, dim3(1), dim3(64), 0, stream, (float*)d_out);
    return;
  }
  hipMemsetAsync(d_ws, 0, (size_t)WS_ZERO, stream);

  KParams P;
  P.memory = (const float*)d_in[0];  P.mels = (const float*)d_in[1];
  P.pw1 = (const float*)d_in[2];     P.pw2 = (const float*)d_in[3];
  P.mem_w = (const float*)d_in[4];   P.qw = (const float*)d_in[5];
  P.vw = (const float*)d_in[6];
  P.aih = (const float*)d_in[7];     P.ahh = (const float*)d_in[8];
  P.abi = (const float*)d_in[9];     P.abh = (const float*)d_in[10];
  P.dih = (const float*)d_in[11];    P.dhh = (const float*)d_in[12];
  P.dbi = (const float*)d_in[13];    P.dbh = (const float*)d_in[14];
  P.prw = (const float*)d_in[15];    P.prb = (const float*)d_in[16];
  P.gw = (const float*)d_in[17];     P.gb = (const float*)d_in[18];
  P.ws = (char*)d_ws; P.out = (float*)d_out;
  tf2x32(0u, 42u, 0u, 0u, P.k10, P.k11);
  tf2x32(0u, 42u, 0u, 1u, P.k20, P.k21);

  hipLaunchKernelGGL(decoder_kernel, dim3(NBLK), dim3(NTHR), 0, stream, P);
}

// Round 7
// 18965.138 us; speedup vs baseline: 1.9359x; 1.3071x over previous
//
#include <hip/hip_runtime.h>

typedef unsigned int u32;
typedef unsigned short u16;
typedef unsigned long long u64;
#define DEV __device__ __forceinline__

// ---------------- sizes ----------------
#define T_DEC 300
#define NB    16
#define T_ENC 200
#define EDIM  512
#define ARNN  1024
#define PDIM  256
#define ADIM  128
#define NMEL  80
#define KATT  1792            // 256 prenet + 512 ctx + 1024 h_att (448 quads)
#define KDEC  2560            // 1024 h_att + 512 ctx + 1024 h_dec (640 quads)
#define NBLK  512             // 2 units/block, 256 thr -> same waves/CU as R6, half traffic
#define NTHR  256
#define SPIN  2000000         // poll-iteration limit

// ---------------- ws byte offsets ----------------
#define WS_S1L    0
#define WS_ABORT  2048
#define WS_S2CNT  2112
#define WS_S2REP  2560
#define WS_ALIGN  4608                      // f32 [2][16][200] = 25600 (att-block-local)
#define WS_XA     30208                     // f32 [2][448][16][4] quads = 229376
#define WS_XD     259584                    // f32 [2][640][16][4] quads = 327680
#define WS_PM     587264                    // u16 [3200][128] = 819200
#define WS_END    1406464
#define WS_ZERO   587264

// quad layout: element (k,b) at float offset (k>>2)*64 + b*4 + (k&3)

// ---------------- out layout (f32 elements) ----------------
#define OUT_GATE  (NB*NMEL*T_DEC)           // 384000
#define OUT_ALIGN (OUT_GATE + NB*T_DEC)     // 388800

// ---------------- helpers ----------------
DEV float bflo(u32 u){ return __uint_as_float(u << 16); }
DEV float bfhi(u32 u){ return __uint_as_float(u & 0xffff0000u); }
DEV u16 f2bf(float f){
  u32 u = __float_as_uint(f);
  return (u16)((u + 0x7fffu + ((u >> 16) & 1u)) >> 16);
}
DEV float fsig(float x){ return 1.0f / (1.0f + __expf(-x)); }
DEV float ftanh(float x){
  float xx = fminf(15.0f, fmaxf(-15.0f, x));
  float e = __expf(2.0f * xx);
  return (e - 1.0f) / (e + 1.0f);
}

// ---- coherence-point accessors (sc0 sc1) ----
DEV void ast (float* p, float v){ __hip_atomic_store(p, v, __ATOMIC_RELAXED, __HIP_MEMORY_SCOPE_AGENT); }
DEV void ast32(u32* p, u32 v)  { __hip_atomic_store(p, v, __ATOMIC_RELAXED, __HIP_MEMORY_SCOPE_AGENT); }
DEV int  ald (const int* p)    { return __hip_atomic_load(p, __ATOMIC_RELAXED, __HIP_MEMORY_SCOPE_AGENT); }
DEV void ald2f(const float* p, float& f0, float& f1){
  u64 v = __hip_atomic_load((const u64*)p, __ATOMIC_RELAXED, __HIP_MEMORY_SCOPE_AGENT);
  f0 = __uint_as_float((u32)v);
  f1 = __uint_as_float((u32)(v >> 32));
}
DEV void ast2f(float* p, float f0, float f1){
  u64 v = (u64)__float_as_uint(f0) | ((u64)__float_as_uint(f1) << 32);
  __hip_atomic_store((u64*)p, v, __ATOMIC_RELAXED, __HIP_MEMORY_SCOPE_AGENT);
}
// wide coherent load (16B). Result valid only after explicit s_waitcnt vmcnt.
DEV void ld16(float4& d, const float* p){
  asm volatile("global_load_dwordx4 %0, %1, off sc0 sc1" : "=v"(d) : "v"(p) : "memory");
}

// ---------------- Threefry-2x32-20 ----------------
__host__ __device__ inline void tf2x32(u32 k0, u32 k1, u32 x0, u32 x1, u32& o0, u32& o1){
  u32 k2 = k0 ^ k1 ^ 0x1BD11BDAu;
  x0 += k0; x1 += k1;
#define TFR(r) { x0 += x1; x1 = (x1 << r) | (x1 >> (32 - r)); x1 ^= x0; }
  TFR(13) TFR(15) TFR(26) TFR(6)  x0 += k1; x1 += k2 + 1u;
  TFR(17) TFR(29) TFR(16) TFR(24) x0 += k2; x1 += k0 + 2u;
  TFR(13) TFR(15) TFR(26) TFR(6)  x0 += k0; x1 += k1 + 3u;
  TFR(17) TFR(29) TFR(16) TFR(24) x0 += k1; x1 += k2 + 4u;
  TFR(13) TFR(15) TFR(26) TFR(6)  x0 += k2; x1 += k0 + 5u;
#undef TFR
  o0 = x0; o1 = x1;
}
DEV bool keep_mask(u32 k0, u32 k1, u32 idx){
  u32 a, b; tf2x32(k0, k1, 0u, idx, a, b);
  return (((a ^ b) >> 31) & 1u) == 0u;
}

// ---------------- params ----------------
struct KParams {
  const float *memory, *mels, *pw1, *pw2, *mem_w, *qw, *vw;
  const float *aih, *ahh, *abi, *abh, *dih, *dhh, *dbi, *dbh;
  const float *prw, *prb, *gw, *gb;
  char* ws; float* out;
  u32 k10, k11, k20, k21;
};

__global__ void sentinel_kernel(float* out){ if (threadIdx.x == 0) out[0] = 123.0f; }

// ---------------- sync primitives (fence-free) ----------------
// 32 S1 leaves, 16 blocks each.
DEV void postS1(int* S1L, int blk, int tid){
  asm volatile("s_waitcnt vmcnt(0)" ::: "memory");
  __syncthreads();
  if (tid == 0)
    (void)__hip_atomic_fetch_add(&S1L[(blk >> 4) * 16], 1, __ATOMIC_RELAXED, __HIP_MEMORY_SCOPE_AGENT);
}

DEV bool waitS1(int* S1L, int* abortf, int target, int tid, float* out){
  int aborted = 0;
  if (tid < 64){
    int tries = 0;
    for (;;){
      int v = (tid < 32) ? ald(&S1L[tid * 16]) : 0x7fffffff;
      if (__all(v >= target)) break;
      if (++tries > SPIN){
        __hip_atomic_store(abortf, 1, __ATOMIC_RELAXED, __HIP_MEMORY_SCOPE_AGENT);
        out[1] = 55.0f; aborted = 1; break;
      }
      if ((tries & 255) == 0 && ald(abortf) != 0){ aborted = 1; break; }
      __builtin_amdgcn_s_sleep(1);
    }
  }
  if (__syncthreads_or(aborted)) return false;
  return true;
}

DEV void postS2(int* s2cnt, int* rep, int t1, int tid){
  asm volatile("s_waitcnt vmcnt(0)" ::: "memory");
  __syncthreads();
  if (tid == 0){
    int old = __hip_atomic_fetch_add(s2cnt, 1, __ATOMIC_RELAXED, __HIP_MEMORY_SCOPE_AGENT);
    if (old == 32 * t1 - 1){
#pragma unroll
      for (int i = 0; i < 32; i++)
        __hip_atomic_store(&rep[i * 16], t1, __ATOMIC_RELAXED, __HIP_MEMORY_SCOPE_AGENT);
    }
  }
}

DEV bool waitRep(int* repline, int* abortf, int target, int tid, float* out){
  int aborted = 0;
  if (tid == 0){
    int tries = 0;
    while (ald(repline) < target){
      if (++tries > SPIN){
        __hip_atomic_store(abortf, 1, __ATOMIC_RELAXED, __HIP_MEMORY_SCOPE_AGENT);
        out[1] = 55.0f; aborted = 1; break;
      }
      if ((tries & 255) == 0 && ald(abortf) != 0){ aborted = 1; break; }
      __builtin_amdgcn_s_sleep(1);
    }
  }
  if (__syncthreads_or(aborted)) return false;
  return true;
}

// ---------------- persistent decoder ----------------
// 512 blocks x 256 thr; block owns units 2blk,2blk+1. Every 16B coherent X load
// feeds BOTH units (32 FMA) -> cross-block traffic 280->140 MB/step. LDS ~79 KB
// -> 2 blocks/CU x 4 waves = 8 waves/CU (same concurrency as R6's 4x2).
__global__ void __launch_bounds__(NTHR, 2) decoder_kernel(KParams P){
  __shared__ __align__(16) u16 WA[448 * 32];   // quad q, unit u: 32 u16 @ q*32+u*16
  __shared__ __align__(16) u16 WD[640 * 32];
  __shared__ __align__(16) float SCR[2048];
  __shared__ float GS[128], HH[32], CATT[32], CDEC[32];
  __shared__ float GBA[8], GBD[8];

  const int blk = blockIdx.x, tid = threadIdx.x;
  int* S1L    = (int*)(P.ws + WS_S1L);
  int* abortf = (int*)(P.ws + WS_ABORT);
  int* S2cnt  = (int*)(P.ws + WS_S2CNT);
  int* S2rep  = (int*)(P.ws + WS_S2REP);
  int* myrep  = &S2rep[(blk & 31) * 16];
  float* ALN = (float*)(P.ws + WS_ALIGN);          // [2][16][200] (att-block-local, plain)
  float* XA  = (float*)(P.ws + WS_XA);             // [2] quads [448][16][4]
  float* XD  = (float*)(P.ws + WS_XD);             // [2] quads [640][16][4]
  u16*   PM  = (u16*)(P.ws + WS_PM);               // [3200][128] bf16 (const after init)
  float* out = P.out;

  // ---- one-time: stage both units' LSTM weights into LDS as bf16 ----
  // layout: u16 index = (k>>2)*32 + u*16 + (k&3)*4 + g
  for (int u = 0; u < 2; u++){
    int j = 2 * blk + u;
#pragma unroll
    for (int g = 0; g < 4; g++){
      const float* rih = P.aih + (size_t)(g * ARNN + j) * 768;
      const float* rhh = P.ahh + (size_t)(g * ARNN + j) * ARNN;
      for (int k = tid; k < KATT; k += NTHR){
        float v = (k < 768) ? rih[k] : rhh[k - 768];
        WA[(k >> 2) * 32 + u * 16 + (k & 3) * 4 + g] = f2bf(v);
      }
      const float* dih = P.dih + (size_t)(g * ARNN + j) * 1536;
      const float* dhh = P.dhh + (size_t)(g * ARNN + j) * ARNN;
      for (int k = tid; k < KDEC; k += NTHR){
        float v = (k < 1536) ? dih[k] : dhh[k - 1536];
        WD[(k >> 2) * 32 + u * 16 + (k & 3) * 4 + g] = f2bf(v);
      }
    }
  }
  if (tid < 8){
    int u = tid >> 2, g = tid & 3, j = 2 * blk + u;
    GBA[tid] = P.abi[g * ARNN + j] + P.abh[g * ARNN + j];
    GBD[tid] = P.dbi[g * ARNN + j] + P.dbh[g * ARNN + j];
  }
  if (tid < 32){ CATT[tid] = 0.f; CDEC[tid] = 0.f; }
  if (blk < 16 && tid == 0) ALN[blk * T_ENC] = 1.0f;   // SMA init, parity 0 (block-local)

  // ---- one-time: processed_memory pm[b*200+te][a], published via sc1 u32 stores ----
  for (int rr = 0; rr < 7; rr++){
    int p = blk + rr * NBLK;
    if (p < NB * T_ENC){
      __syncthreads();
      if (tid < 128){
        float4 v = ((const float4*)(P.memory + (size_t)p * EDIM))[tid];
        SCR[4 * tid] = v.x; SCR[4 * tid + 1] = v.y;
        SCR[4 * tid + 2] = v.z; SCR[4 * tid + 3] = v.w;
      }
      __syncthreads();
      if (tid < 128){
        const float4* w4 = (const float4*)(P.mem_w + (size_t)tid * EDIM);
        float s = 0.f;
        for (int j = 0; j < 128; j++){
          float4 w = w4[j];
          s = fmaf(w.x, SCR[4 * j], s);     s = fmaf(w.y, SCR[4 * j + 1], s);
          s = fmaf(w.z, SCR[4 * j + 2], s); s = fmaf(w.w, SCR[4 * j + 3], s);
        }
        SCR[512 + tid] = s;
      }
      __syncthreads();
      if (tid < 64){
        u32 w2 = (u32)f2bf(SCR[512 + 2 * tid]) | ((u32)f2bf(SCR[512 + 2 * tid + 1]) << 16);
        ast32((u32*)PM + (size_t)p * 64 + tid, w2);
      }
    }
  }

  const int b16 = tid & 15, ks = tid >> 4;   // batch lane, quad-slice (16 slices)
  const uint4* WA4 = (const uint4*)WA;       // quad q, unit u -> WA4[q*4+2u], [q*4+2u+1]
  const uint4* WD4 = (const uint4*)WD;

#define CONSUME2(Wp, Xv, qc)                                                       \
  { float4 x_ = (Xv);                                                              \
    uint4 w01 = (Wp)[(qc) * 4 + 0], w23 = (Wp)[(qc) * 4 + 1];                      \
    uint4 v01 = (Wp)[(qc) * 4 + 2], v23 = (Wp)[(qc) * 4 + 3];                      \
    a00 = fmaf(bflo(w01.x), x_.x, a00); a00 = fmaf(bflo(w01.z), x_.y, a00);        \
    a00 = fmaf(bflo(w23.x), x_.z, a00); a00 = fmaf(bflo(w23.z), x_.w, a00);        \
    a01 = fmaf(bfhi(w01.x), x_.x, a01); a01 = fmaf(bfhi(w01.z), x_.y, a01);        \
    a01 = fmaf(bfhi(w23.x), x_.z, a01); a01 = fmaf(bfhi(w23.z), x_.w, a01);        \
    a02 = fmaf(bflo(w01.y), x_.x, a02); a02 = fmaf(bflo(w01.w), x_.y, a02);        \
    a02 = fmaf(bflo(w23.y), x_.z, a02); a02 = fmaf(bflo(w23.w), x_.w, a02);        \
    a03 = fmaf(bfhi(w01.y), x_.x, a03); a03 = fmaf(bfhi(w01.w), x_.y, a03);        \
    a03 = fmaf(bfhi(w23.y), x_.z, a03); a03 = fmaf(bfhi(w23.w), x_.w, a03);        \
    a10 = fmaf(bflo(v01.x), x_.x, a10); a10 = fmaf(bflo(v01.z), x_.y, a10);        \
    a10 = fmaf(bflo(v23.x), x_.z, a10); a10 = fmaf(bflo(v23.z), x_.w, a10);        \
    a11 = fmaf(bfhi(v01.x), x_.x, a11); a11 = fmaf(bfhi(v01.z), x_.y, a11);        \
    a11 = fmaf(bfhi(v23.x), x_.z, a11); a11 = fmaf(bfhi(v23.z), x_.w, a11);        \
    a12 = fmaf(bflo(v01.y), x_.x, a12); a12 = fmaf(bflo(v01.w), x_.y, a12);        \
    a12 = fmaf(bflo(v23.y), x_.z, a12); a12 = fmaf(bflo(v23.w), x_.w, a12);        \
    a13 = fmaf(bfhi(v01.y), x_.x, a13); a13 = fmaf(bfhi(v01.w), x_.y, a13);        \
    a13 = fmaf(bfhi(v23.y), x_.z, a13); a13 = fmaf(bfhi(v23.w), x_.w, a13); }

#define REDUCE_AND_CELL(GB, CST)                                                   \
  __syncthreads();                                                                 \
  SCR[tid * 8 + 0] = a00; SCR[tid * 8 + 1] = a01;                                  \
  SCR[tid * 8 + 2] = a02; SCR[tid * 8 + 3] = a03;                                  \
  SCR[tid * 8 + 4] = a10; SCR[tid * 8 + 5] = a11;                                  \
  SCR[tid * 8 + 6] = a12; SCR[tid * 8 + 7] = a13;                                  \
  __syncthreads();                                                                 \
  if (tid < 128){                                                                  \
    int b_ = tid & 15, u_ = (tid >> 4) & 1, g_ = tid >> 5;                         \
    float s_ = 0.f;                                                                \
    _Pragma("unroll")                                                              \
    for (int q_ = 0; q_ < 16; q_++) s_ += SCR[(q_ * 16 + b_) * 8 + u_ * 4 + g_];   \
    GS[tid] = s_;                                                                  \
  }                                                                                \
  __syncthreads();                                                                 \
  if (tid < 32){                                                                   \
    int u_ = tid >> 4, b_ = tid & 15, o_ = b_ + 16 * u_;                           \
    float gi = GS[o_]      + GB[4 * u_ + 0];                                       \
    float gf = GS[o_ + 32] + GB[4 * u_ + 1];                                       \
    float gg = GS[o_ + 64] + GB[4 * u_ + 2];                                       \
    float go = GS[o_ + 96] + GB[4 * u_ + 3];                                       \
    float cn = fsig(gf) * CST[tid] + fsig(gi) * ftanh(gg);                         \
    CST[tid] = cn;                                                                 \
    HH[tid] = fsig(go) * ftanh(cn);                                                \
  }                                                                                \
  __syncthreads();

  for (int t = 0; t < T_DEC; t++){
    const int rp = t & 1, wp = rp ^ 1;
    const int t1 = t + 1;
    float* XAr = XA + rp * (KATT * 16);
    float* XAw = XA + wp * (KATT * 16);
    float* XDr = XD + rp * (KDEC * 16);
    float* XDw = XD + wp * (KDEC * 16);
    const int hpos = (2 * blk) & 3;

    // ======== stage 1: attention LSTM, units 2blk,2blk+1 — 28 quads, 4 groups of 7 ========
    {
      float a00 = 0.f, a01 = 0.f, a02 = 0.f, a03 = 0.f;
      float a10 = 0.f, a11 = 0.f, a12 = 0.f, a13 = 0.f;
      const float* xb = XAr + b16 * 4;
      float4 X0[7], X1[7];
      asm volatile("s_waitcnt vmcnt(0)" ::: "memory");
#pragma unroll
      for (int j = 0; j < 7; j++) ld16(X0[j], xb + (ks + 16 * j) * 64);
#pragma unroll
      for (int g = 0; g < 4; g++){
        float4* C = (g & 1) ? X1 : X0;
        float4* N = (g & 1) ? X0 : X1;
        if (g < 3){
#pragma unroll
          for (int j = 0; j < 7; j++) ld16(N[j], xb + (ks + 16 * (7 * (g + 1) + j)) * 64);
          asm volatile("s_waitcnt vmcnt(7)" ::: "memory");
        } else {
          asm volatile("s_waitcnt vmcnt(0)" ::: "memory");
        }
        __builtin_amdgcn_sched_barrier(0);
#pragma unroll
        for (int j = 0; j < 7; j++) CONSUME2(WA4, C[j], ks + 16 * (7 * g + j));
      }
      REDUCE_AND_CELL(GBA, CATT)
      if (tid < 16){
        ast2f(&XAw[(192 + (blk >> 1)) * 64 + tid * 4 + hpos], HH[tid], HH[16 + tid]);
        ast2f(&XDw[(blk >> 1) * 64 + tid * 4 + hpos],        HH[tid], HH[16 + tid]);
      }
    }
    postS1(S1L, blk, tid);

    if (blk < 16){
      // ---- attention chain, batch b = blk ----
      if (!waitS1(S1L, abortf, 16 * t1, tid, out)) return;
      const int b = blk;
      {
        const float* qa = XAw + (192 + tid) * 64 + b * 4;   // h_att quads 192..447
        float h0, h1, h2, h3;
        ald2f(qa, h0, h1); ald2f(qa + 2, h2, h3);
        SCR[4 * tid] = h0; SCR[4 * tid + 1] = h1; SCR[4 * tid + 2] = h2; SCR[4 * tid + 3] = h3;
      }
      __syncthreads();
      {
        int row = tid & 127, half = tid >> 7;
        const float4* q4 = (const float4*)(P.qw + (size_t)row * ARNN + half * 512);
        const float* xx = SCR + half * 512;
        float pq = 0.f;
        for (int j = 0; j < 128; j++){
          float4 q = q4[j];
          pq = fmaf(q.x, xx[4 * j], pq);     pq = fmaf(q.y, xx[4 * j + 1], pq);
          pq = fmaf(q.z, xx[4 * j + 2], pq); pq = fmaf(q.w, xx[4 * j + 3], pq);
        }
        SCR[1024 + half * 128 + row] = pq;        // disjoint from [0,1024)
      }
      if (tid < 128) SCR[1280 + tid] = P.vw[tid];
      __syncthreads();
      if (tid < 128) SCR[1024 + tid] = SCR[1024 + tid] + SCR[1152 + tid];
      __syncthreads();
      if (tid < T_ENC){
        const u32* pmr = (const u32*)(PM + (size_t)(b * T_ENC + tid) * 128);  // plain (const)
        float e = 0.f;
        for (int a2 = 0; a2 < 64; a2++){
          u32 pv = pmr[a2];
          e = fmaf(SCR[1280 + 2 * a2],     ftanh(SCR[1024 + 2 * a2]     + bflo(pv)), e);
          e = fmaf(SCR[1280 + 2 * a2 + 1], ftanh(SCR[1024 + 2 * a2 + 1] + bfhi(pv)), e);
        }
        SCR[1408 + tid] = fsig(e);
      }
      __syncthreads();
      {
        const float* alr = ALN + rp * (NB * T_ENC) + b * T_ENC;   // block-local, plain
        float*       alw = ALN + wp * (NB * T_ENC) + b * T_ENC;
        if (tid < T_ENC){
          float an = alr[tid] * SCR[1408 + tid];
          if (tid > 0) an += alr[tid - 1] * (1.f - SCR[1408 + tid - 1]);
          SCR[1664 + tid] = an;
          alw[tid] = an;
          out[OUT_ALIGN + (size_t)(b * T_DEC + t) * T_ENC + tid] = an;
        }
      }
      __syncthreads();
      {
        const float2* mb = (const float2*)(P.memory + (size_t)b * T_ENC * EDIM);  // plain (const)
        float c0 = 0.f, c1 = 0.f;                  // e-pair (2tid, 2tid+1)
        for (int s2 = 0; s2 < T_ENC; s2++){
          float as = SCR[1664 + s2];
          float2 m1 = mb[(size_t)s2 * 256 + tid];
          c0 = fmaf(m1.x, as, c0); c1 = fmaf(m1.y, as, c1);
        }
        int qh = tid >> 1, pos = 2 * (tid & 1);
        ast2f(&XAw[(64  + qh) * 64 + b * 4 + pos], c0, c1);   // ctx rows 256+2tid
        ast2f(&XDw[(256 + qh) * 64 + b * 4 + pos], c0, c1);   // ctx rows 1024+2tid
      }
      postS2(S2cnt, S2rep, t1, tid);
    } else if (blk < 32){
      // ---- prenet for step t+1: no wait (anti-dep covered by prior waitRep) ----
      const int b = blk - 16;
      if (t < T_DEC - 1){
        const int tt = t + 1;
        if (tid < NMEL) SCR[tid] = P.mels[(size_t)(b * NMEL + tid) * T_DEC + t];  // plain (const)
        __syncthreads();
        {
          const float* wr = P.pw1 + (size_t)tid * NMEL;      // layer1 out p2 = tid
          float s = 0.f;
          for (int m2 = 0; m2 < NMEL; m2++) s = fmaf(wr[m2], SCR[m2], s);
          s = fmaxf(s, 0.f);
          u32 idx = (u32)((tt * NB + b) * PDIM + tid);
          SCR[256 + tid] = keep_mask(P.k10, P.k11, idx) ? 2.f * s : 0.f;
        }
        __syncthreads();
        {
          const float* wr = P.pw2 + (size_t)tid * PDIM;      // layer2 out q = tid
          float s = 0.f;
          for (int p3 = 0; p3 < PDIM; p3++) s = fmaf(wr[p3], SCR[256 + p3], s);
          s = fmaxf(s, 0.f);
          u32 idx = (u32)((tt * NB + b) * PDIM + tid);
          ast(&XAw[(tid >> 2) * 64 + b * 4 + (tid & 3)],
              keep_mask(P.k20, P.k21, idx) ? 2.f * s : 0.f);
        }
      }
      postS2(S2cnt, S2rep, t1, tid);
      // ---- projection(t-1): needs all stage3(t-1) done == all S1 leaves >= 16*t1 ----
      if (t > 0){
        if (!waitS1(S1L, abortf, 16 * t1, tid, out)) return;
        {
          const float* qa = XDr + (384 + tid) * 64 + b * 4;  // h_dec quads 384..639
          float h0, h1, h2, h3;
          ald2f(qa, h0, h1); ald2f(qa + 2, h2, h3);
          SCR[4 * tid] = h0; SCR[4 * tid + 1] = h1; SCR[4 * tid + 2] = h2; SCR[4 * tid + 3] = h3;
        }
        __syncthreads();
        float s = 0.f; const float* wr = 0;
        if (tid < 81){
          wr = (tid < 80) ? P.prw + (size_t)tid * 1536 : P.gw;    // plain (const)
          s = (tid < 80) ? P.prb[tid] : P.gb[0];
          for (int k = 0; k < 1024; k++) s = fmaf(wr[k], SCR[k], s);
        }
        __syncthreads();
        if (tid < 128){
          const float* qa = XDr + (256 + tid) * 64 + b * 4;  // ctx quads 256..383
          float f0, f1, f2, f3;
          ald2f(qa, f0, f1); ald2f(qa + 2, f2, f3);
          SCR[4 * tid] = f0; SCR[4 * tid + 1] = f1; SCR[4 * tid + 2] = f2; SCR[4 * tid + 3] = f3;
        }
        __syncthreads();
        if (tid < 81){
          for (int e = 0; e < 512; e++) s = fmaf(wr[1024 + e], SCR[e], s);
          if (tid < 80) out[(size_t)(b * NMEL + tid) * T_DEC + (t - 1)] = s;
          else          out[OUT_GATE + (size_t)b * T_DEC + (t - 1)] = s;
        }
        __syncthreads();
      }
    }

    if (!waitRep(myrep, abortf, t1, tid, out)) return;

    // ======== stage 3: decoder LSTM, units 2blk,2blk+1 — 40 quads, 5 groups of 8 ========
    {
      float a00 = 0.f, a01 = 0.f, a02 = 0.f, a03 = 0.f;
      float a10 = 0.f, a11 = 0.f, a12 = 0.f, a13 = 0.f;
      const float* xw = XDw + b16 * 4;
      const float* xr = XDr + b16 * 4;
      float4 X0[8], X1[8];
      asm volatile("s_waitcnt vmcnt(0)" ::: "memory");
#pragma unroll
      for (int j = 0; j < 8; j++) ld16(X0[j], xw + (ks + 16 * j) * 64);
#pragma unroll
      for (int g = 0; g < 5; g++){
        float4* C = (g & 1) ? X1 : X0;
        float4* N = (g & 1) ? X0 : X1;
        if (g < 4){
          const float* src = (g + 1 < 3) ? xw : xr;    // groups 3,4 (quads>=384) in XDr
#pragma unroll
          for (int j = 0; j < 8; j++) ld16(N[j], src + (ks + 16 * (8 * (g + 1) + j)) * 64);
          asm volatile("s_waitcnt vmcnt(8)" ::: "memory");
        } else {
          asm volatile("s_waitcnt vmcnt(0)" ::: "memory");
        }
        __builtin_amdgcn_sched_barrier(0);
#pragma unroll
        for (int j = 0; j < 8; j++) CONSUME2(WD4, C[j], ks + 16 * (8 * g + j));
      }
      REDUCE_AND_CELL(GBD, CDEC)
      if (tid < 16)
        ast2f(&XDw[(384 + (blk >> 1)) * 64 + tid * 4 + hpos], HH[tid], HH[16 + tid]);
    }
    // stage3's h stores drained by next iteration's postS1 vmcnt(0).
  }

  // ---- epilogue: final S1 post, then projection for t = 299 (parity 0) ----
  postS1(S1L, blk, tid);
  if (blk >= 16 && blk < 32){
    if (!waitS1(S1L, abortf, 16 * (T_DEC + 1), tid, out)) return;
    const int b = blk - 16;
    const float* XD0 = XD;   // parity 0
    {
      const float* qa = XD0 + (384 + tid) * 64 + b * 4;
      float h0, h1, h2, h3;
      ald2f(qa, h0, h1); ald2f(qa + 2, h2, h3);
      SCR[4 * tid] = h0; SCR[4 * tid + 1] = h1; SCR[4 * tid + 2] = h2; SCR[4 * tid + 3] = h3;
    }
    __syncthreads();
    float s = 0.f; const float* wr = 0;
    if (tid < 81){
      wr = (tid < 80) ? P.prw + (size_t)tid * 1536 : P.gw;
      s = (tid < 80) ? P.prb[tid] : P.gb[0];
      for (int k = 0; k < 1024; k++) s = fmaf(wr[k], SCR[k], s);
    }
    __syncthreads();
    if (tid < 128){
      const float* qa = XD0 + (256 + tid) * 64 + b * 4;
      float f0, f1, f2, f3;
      ald2f(qa, f0, f1); ald2f(qa + 2, f2, f3);
      SCR[4 * tid] = f0; SCR[4 * tid + 1] = f1; SCR[4 * tid + 2] = f2; SCR[4 * tid + 3] = f3;
    }
    __syncthreads();
    if (tid < 81){
      for (int e = 0; e < 512; e++) s = fmaf(wr[1024 + e], SCR[e], s);
      if (tid < 80) out[(size_t)(b * NMEL + tid) * T_DEC + (T_DEC - 1)] = s;
      else          out[OUT_GATE + (size_t)b * T_DEC + (T_DEC - 1)] = s;
    }
  }
}

// ---------------- launch ----------------
extern "C" void kernel_launch(void* const* d_in, const int* in_sizes, int n_in,
                              void* d_out, int out_size, void* d_ws, size_t ws_size,
                              hipStream_t stream){
  if (ws_size < (size_t)WS_END){
    hipLaunchKernelGGL(sentinel_kernel, dim3(1), dim3(64), 0, stream, (float*)d_out);
    return;
  }
  hipMemsetAsync(d_ws, 0, (size_t)WS_ZERO, stream);

  KParams P;
  P.memory = (const float*)d_in[0];  P.mels = (const float*)d_in[1];
  P.pw1 = (const float*)d_in[2];     P.pw2 = (const float*)d_in[3];
  P.mem_w = (const float*)d_in[4];   P.qw = (const float*)d_in[5];
  P.vw = (const float*)d_in[6];
  P.aih = (const float*)d_in[7];     P.ahh = (const float*)d_in[8];
  P.abi = (const float*)d_in[9];     P.abh = (const float*)d_in[10];
  P.dih = (const float*)d_in[11];    P.dhh = (const float*)d_in[12];
  P.dbi = (const float*)d_in[13];    P.dbh = (const float*)d_in[14];
  P.prw = (const float*)d_in[15];    P.prb = (const float*)d_in[16];
  P.gw = (const float*)d_in[17];     P.gb = (const float*)d_in[18];
  P.ws = (char*)d_ws; P.out = (float*)d_out;
  tf2x32(0u, 42u, 0u, 0u, P.k10, P.k11);
  tf2x32(0u, 42u, 0u, 1u, P.k20, P.k21);

  hipLaunchKernelGGL(decoder_kernel, dim3(NBLK), dim3(NTHR), 0, stream, P);
}